// Round 15
// baseline (196.113 us; speedup 1.0000x reference)
//
#include <hip/hip_runtime.h>
#include <hip/hip_bf16.h>
#include <hip/hip_cooperative_groups.h>
#include <math.h>

namespace cg = cooperative_groups;

typedef unsigned int uint32;
typedef unsigned short ushort_t;
typedef __attribute__((ext_vector_type(8))) short s8v;
typedef __attribute__((ext_vector_type(16))) float f16v;
typedef __attribute__((ext_vector_type(2))) unsigned int u2v;

// Problem constants
#define LH 4
#define RH 4
#define DD 64
#define BB 2
#define TT 96
#define NTOK (BB*TT)           // 192
#define HEADS 16
#define VHEADS 10              // heads with r <= l
#define INV_H 0.0625f
#define LOG2E 1.4426950408889634f
#define QKV_TASKS 288          // 1152 waves / 4
#define ATT_TASKS (BB*VHEADS*(TT/2))   // 960
#define OUT_TASKS (NTOK*2/4)   // 96
#define P0_TASKS (12 + 48)     // 12 wprep + 48 zerofill

struct U4 { uint32 x, y, z, w; };

__device__ __forceinline__ uint32 f2bf(float f) {
    return (uint32)__builtin_bit_cast(ushort_t, __float2bfloat16(f));
}
__device__ __forceinline__ uint32 pkbf(float lo, float hi) {
    return f2bf(lo) | (f2bf(hi) << 16);
}
__device__ __forceinline__ float bf2f(uint32 u) {
    return __uint_as_float(u << 16);
}
__device__ __forceinline__ void hl_pair(float v0, float v1, uint32 &hw, uint32 &lw) {
    uint32 h0 = f2bf(v0), h1 = f2bf(v1);
    hw = h0 | (h1 << 16);
    lw = pkbf(v0 - bf2f(h0), v1 - bf2f(h1));
}
// exchange lanes[0:31] of a with lanes[32:63] of b — verified for A-frags (R10)
__device__ __forceinline__ void hswap(uint32 &a, uint32 &b, int h) {
#if __has_builtin(__builtin_amdgcn_permlane32_swap)
    u2v rr = __builtin_amdgcn_permlane32_swap(a, b, false, false);
    a = rr.x; b = rr.y;
#else
    uint32 xa = (uint32)__shfl_xor((int)a, 32, 64);
    uint32 xb = (uint32)__shfl_xor((int)b, 32, 64);
    uint32 na = (h == 0) ? xb : a;
    uint32 nb = (h == 0) ? b  : xa;
    a = na; b = nb;
#endif
}

// ---------------------------------------------------------------------------
// Fused layer: P0 wprep+zerofill -> P1 qkv -> P2 attn -> P3 out.
// Phase bodies verbatim from R14's individually verified kernels.
// ---------------------------------------------------------------------------
__global__ __launch_bounds__(256, 2) void fused_all(
    const float* __restrict__ Xq, const float* __restrict__ Xk, const float* __restrict__ Xv,
    const float* __restrict__ Wq_row, const float* __restrict__ Wq_col, const float* __restrict__ bq,
    const float* __restrict__ Wk_row, const float* __restrict__ Wk_col, const float* __restrict__ bk,
    const float* __restrict__ Wv_row, const float* __restrict__ Wv_col, const float* __restrict__ bv,
    const float* __restrict__ Wo_row, const float* __restrict__ Wo_col, const float* __restrict__ bo,
    ushort_t* __restrict__ q_bf, ushort_t* __restrict__ k_bf, ushort_t* __restrict__ vt_bf,
    float* __restrict__ att,
    ushort_t* __restrict__ wct, ushort_t* __restrict__ wrt, float* __restrict__ bT,
    ushort_t* __restrict__ woct_h, ushort_t* __restrict__ woct_l,
    ushort_t* __restrict__ wort_h, ushort_t* __restrict__ wort_l, float* __restrict__ boT,
    float* __restrict__ out)
{
    __shared__ union LU {
        float t1[4][32][68];                              // qkv / out slab (34816 B)
        struct { float z[4][64][9]; float pv[4][64][17]; } at;  // attn (26624 B)
    } L;

    cg::grid_group grid = cg::this_grid();
    const int tid = threadIdx.x;
    const int nb = gridDim.x;
    const f16v fz = {0,0,0,0,0,0,0,0,0,0,0,0,0,0,0,0};

    // ================= P0: weight prep + att zerofill =================
    for (int task = blockIdx.x; task < P0_TASKS; task += nb) {
        if (task < 12) {
            #pragma unroll
            for (int e = 0; e < 16; ++e) {
                const int idx = e * 256 + tid;
                const int src = (idx & 63) * 64 + (idx >> 6);
                switch (task) {
                case 0: wct[idx]          = (ushort_t)f2bf(Wq_col[src]); break;
                case 1: wct[4096 + idx]   = (ushort_t)f2bf(Wk_col[src]); break;
                case 2: wct[8192 + idx]   = (ushort_t)f2bf(Wv_col[src]); break;
                case 3: wrt[idx]          = (ushort_t)f2bf(Wq_row[src]); break;
                case 4: wrt[4096 + idx]   = (ushort_t)f2bf(Wk_row[src]); break;
                case 5: wrt[8192 + idx]   = (ushort_t)f2bf(Wv_row[src]); break;
                case 6: bT[idx]           = bq[src]; break;
                case 7: bT[4096 + idx]    = bk[src]; break;
                case 8: bT[8192 + idx]    = bv[src]; break;
                case 9: {
                    float v = Wo_col[src];
                    uint32 hh = f2bf(v);
                    woct_h[idx] = (ushort_t)hh;
                    woct_l[idx] = (ushort_t)f2bf(v - bf2f(hh));
                    break; }
                case 10: {
                    float v = Wo_row[src];
                    uint32 hh = f2bf(v);
                    wort_h[idx] = (ushort_t)hh;
                    wort_l[idx] = (ushort_t)f2bf(v - bf2f(hh));
                    break; }
                default: boT[idx] = bo[src]; break;
                }
            }
        } else {
            const int zb = task - 12;
            float4* a4 = (float4*)att;
            #pragma unroll
            for (int k2 = 0; k2 < 16; ++k2)
                a4[(size_t)zb * 4096 + k2 * 256 + tid] = float4{0.f, 0.f, 0.f, 0.f};
        }
    }
    grid.sync();

    // ================= P1: q/k/v projections (MFMA, R13-proven) =================
    for (int task = blockIdx.x; task < QKV_TASKS; task += nb) {
        const int wv = tid >> 6;
        const int wtask = task * 4 + wv;                 // 0..1151
        const int proj = wtask / (NTOK * 2);
        const int rem  = wtask % (NTOK * 2);
        const int token = rem >> 1;
        const int ch = rem & 1;
        const int lane = tid & 63;
        const int c5 = lane & 31, h = lane >> 5;
        const int c = ch * 32 + c5;
        const int bI = token / TT, t = token % TT;

        const float* X = (proj == 0) ? Xq : (proj == 1) ? Xk : Xv;
        const float* Xp = X + (size_t)token * 4096;
        const ushort_t* wc = wct + proj * 4096;
        const ushort_t* wr = wrt + proj * 4096;
        const float*    bt = bT + proj * 4096;
        const float scale = (proj == 0) ? (INV_H * INV_H * LOG2E) : INV_H;

        f16v t1_0 = fz, t1_1 = fz;
        #pragma unroll
        for (int n = 0; n < 4; ++n) {
            s8v bf = *(const s8v*)(wc + c * 64 + n * 16 + 8 * h);
            {
                const float* xr = Xp + (size_t)c5 * 64 + n * 16 + 8 * h;
                float4 xa = *(const float4*)xr, xb = *(const float4*)(xr + 4);
                U4 u = { pkbf(xa.x, xa.y), pkbf(xa.z, xa.w), pkbf(xb.x, xb.y), pkbf(xb.z, xb.w) };
                t1_0 = __builtin_amdgcn_mfma_f32_32x32x16_bf16(__builtin_bit_cast(s8v, u), bf, t1_0, 0, 0, 0);
            }
            {
                const float* xr = Xp + (size_t)(32 + c5) * 64 + n * 16 + 8 * h;
                float4 xa = *(const float4*)xr, xb = *(const float4*)(xr + 4);
                U4 u = { pkbf(xa.x, xa.y), pkbf(xa.z, xa.w), pkbf(xb.x, xb.y), pkbf(xb.z, xb.w) };
                t1_1 = __builtin_amdgcn_mfma_f32_32x32x16_bf16(__builtin_bit_cast(s8v, u), bf, t1_1, 0, 0, 0);
            }
        }

        #pragma unroll
        for (int tt = 0; tt < 16; ++tt) {
            const int i = (tt & 3) + 8 * (tt >> 2) + 4 * h;
            L.t1[wv][c5][i]      = t1_0[tt];
            L.t1[wv][c5][32 + i] = t1_1[tt];
        }
        __syncthreads();

        s8v bfr[4];
        #pragma unroll
        for (int n = 0; n < 4; ++n) {
            const float* p = &L.t1[wv][c5][n * 16 + 8 * h];
            float4 xa = *(const float4*)p, xb = *(const float4*)(p + 4);
            U4 u = { pkbf(xa.x, xa.y), pkbf(xa.z, xa.w), pkbf(xb.x, xb.y), pkbf(xb.z, xb.w) };
            bfr[n] = __builtin_bit_cast(s8v, u);
        }

        #pragma unroll
        for (int At = 0; At < 2; ++At) {
            f16v y = fz;
            #pragma unroll
            for (int n = 0; n < 4; ++n) {
                s8v af = *(const s8v*)(wr + (size_t)(32 * At + c5) * 64 + n * 16 + 8 * h);
                y = __builtin_amdgcn_mfma_f32_32x32x16_bf16(af, bfr[n], y, 0, 0, 0);
            }
            #pragma unroll
            for (int rg = 0; rg < 4; ++rg) {
                float4 bv = *(const float4*)(bt + c * 64 + 32 * At + 8 * rg + 4 * h);
                float be[4] = {bv.x, bv.y, bv.z, bv.w};
                #pragma unroll
                for (int e = 0; e < 4; ++e) {
                    const int a = 32 * At + 8 * rg + 4 * h + e;
                    const float val = (y[rg * 4 + e] + be[e]) * scale;
                    const ushort_t ov = (ushort_t)f2bf(val);
                    const size_t base =
                        ((size_t)((bI * HEADS + (a >> 4) * RH + (c >> 4)) * TT + t)) * 256;
                    if (proj == 0)      q_bf[base + (a & 15) * 16 + (c & 15)] = ov;
                    else if (proj == 1) k_bf[base + (a & 15) * 16 + (c & 15)] = ov;
                    else                vt_bf[base + (c & 15) * 16 + (a & 15)] = ov;
                }
            }
        }
        __syncthreads();
    }
    grid.sync();

    // ================= P2: attention (MFMA v2, R10-proven) =================
    for (int task = blockIdx.x; task < ATT_TASKS; task += nb) {
        const int ip = task % (TT / 2);
        const int vh = (task / (TT / 2)) % VHEADS;
        const int bI = task / ((TT / 2) * VHEADS);
        const int l = (vh >= 1) + (vh >= 3) + (vh >= 6);
        const int r = vh - (l * (l + 1)) / 2;
        const int head = l * RH + r;
        const int i0 = ip * 2;
        const int lane = tid & 63;
        const int wv = tid >> 6;
        const int c5 = lane & 31;
        const int h  = lane >> 5;

        const size_t hb = (size_t)(bI * HEADS + head) * TT * 256;
        const int frow = (c5 & 15) * 16 + 8 * h;

        s8v qf = *(const s8v*)(q_bf + hb + (size_t)(i0 + (c5 >> 4)) * 256 + frow);
        const ushort_t* kb = k_bf + hb + frow;
        const ushort_t* vb = vt_bf + hb + frow;

        const int jb = wv * (TT / 4);

        float ls[8] = {0,0,0,0,0,0,0,0};
        #pragma unroll 3
        for (int jp = 0; jp < 12; ++jp) {
            const int j0g = jb + jp * 2;
            s8v kf = *(const s8v*)(kb + (size_t)(j0g + (c5 >> 4)) * 256);
            f16v d = __builtin_amdgcn_mfma_f32_32x32x16_bf16(kf, qf, fz, 0, 0, 0);
            #pragma unroll
            for (int t = 0; t < 8; ++t)
                ls[t] += exp2f(d[t]) + exp2f(d[t + 8]);
        }
        #pragma unroll
        for (int t = 0; t < 8; ++t) L.at.z[wv][lane][t] = ls[t];
        __syncthreads();
        float inv[8];
        #pragma unroll
        for (int t = 0; t < 8; ++t) {
            float s = L.at.z[0][lane][t] + L.at.z[1][lane][t]
                    + L.at.z[2][lane][t] + L.at.z[3][lane][t];
            inv[t] = 1.f / s;
        }

        f16v pv = fz;
        #pragma unroll 2
        for (int jp = 0; jp < 12; ++jp) {
            const int j0g = jb + jp * 2;
            s8v kf = *(const s8v*)(kb + (size_t)(j0g + (c5 >> 4)) * 256);
            f16v d = __builtin_amdgcn_mfma_f32_32x32x16_bf16(kf, qf, fz, 0, 0, 0);
            float w[16];
            #pragma unroll
            for (int t = 0; t < 8; ++t) {
                w[t]     = exp2f(d[t])     * inv[t];
                w[t + 8] = exp2f(d[t + 8]) * inv[t];
            }
            uint32 A0 = pkbf(w[0],  w[1]),  A1 = pkbf(w[2],  w[3]);
            uint32 A2 = pkbf(w[4],  w[5]),  A3 = pkbf(w[6],  w[7]);
            uint32 B0 = pkbf(w[8],  w[9]),  B1 = pkbf(w[10], w[11]);
            uint32 B2 = pkbf(w[12], w[13]), B3 = pkbf(w[14], w[15]);
            hswap(A2, A0, h); hswap(A3, A1, h);
            hswap(B2, B0, h); hswap(B3, B1, h);
            U4 fa = {A0, A1, A2, A3};
            U4 fb = {B0, B1, B2, B3};
            s8v vf0 = *(const s8v*)(vb + (size_t)(j0g + 0) * 256);
            s8v vf1 = *(const s8v*)(vb + (size_t)(j0g + 1) * 256);
            pv = __builtin_amdgcn_mfma_f32_32x32x16_bf16(__builtin_bit_cast(s8v, fa), vf0, pv, 0, 0, 0);
            pv = __builtin_amdgcn_mfma_f32_32x32x16_bf16(__builtin_bit_cast(s8v, fb), vf1, pv, 0, 0, 0);
        }

        #pragma unroll
        for (int t = 0; t < 16; ++t) L.at.pv[wv][lane][t] = pv[t];
        __syncthreads();

        if (c5 < 16) {
            #pragma unroll
            for (int rr = 0; rr < 4; ++rr) {
                const int reg = wv * 4 + rr;
                float v = L.at.pv[0][lane][reg] + L.at.pv[1][lane][reg]
                        + L.at.pv[2][lane][reg] + L.at.pv[3][lane][reg];
                const int row = rr + 8 * wv + 4 * h;
                const int i = row >> 4, p = row & 15;
                att[((size_t)(bI * TT + i0 + i) * DD + l * 16 + p) * DD + r * 16 + c5] = v;
            }
        }
        __syncthreads();
    }
    grid.sync();

    // ================= P3: out-projection (hi/lo MFMA, R14-proven) =================
    for (int task = blockIdx.x; task < OUT_TASKS; task += nb) {
        const int wv = tid >> 6;
        const int otask = task * 4 + wv;                 // 0..383
        const int token = otask >> 1, ch = otask & 1;
        const int lane = tid & 63;
        const int c5 = lane & 31, h = lane >> 5;
        const int c = ch * 32 + c5;

        const float* Xp = att + (size_t)token * 4096;

        f16v t1_0 = fz, t1_1 = fz;
        #pragma unroll
        for (int n = 0; n < 4; ++n) {
            s8v bh = *(const s8v*)(woct_h + c * 64 + n * 16 + 8 * h);
            s8v bl = *(const s8v*)(woct_l + c * 64 + n * 16 + 8 * h);
            #pragma unroll
            for (int T = 0; T < 2; ++T) {
                const float* xr = Xp + (size_t)(32 * T + c5) * 64 + n * 16 + 8 * h;
                float4 xa = *(const float4*)xr, xb = *(const float4*)(xr + 4);
                uint32 hw0, lw0, hw1, lw1, hw2, lw2, hw3, lw3;
                hl_pair(xa.x, xa.y, hw0, lw0);
                hl_pair(xa.z, xa.w, hw1, lw1);
                hl_pair(xb.x, xb.y, hw2, lw2);
                hl_pair(xb.z, xb.w, hw3, lw3);
                U4 uh = {hw0, hw1, hw2, hw3}, ul = {lw0, lw1, lw2, lw3};
                s8v ah = __builtin_bit_cast(s8v, uh), al = __builtin_bit_cast(s8v, ul);
                f16v acc = (T == 0) ? t1_0 : t1_1;
                acc = __builtin_amdgcn_mfma_f32_32x32x16_bf16(ah, bh, acc, 0, 0, 0);
                acc = __builtin_amdgcn_mfma_f32_32x32x16_bf16(al, bh, acc, 0, 0, 0);
                acc = __builtin_amdgcn_mfma_f32_32x32x16_bf16(ah, bl, acc, 0, 0, 0);
                if (T == 0) t1_0 = acc; else t1_1 = acc;
            }
        }

        #pragma unroll
        for (int tt = 0; tt < 16; ++tt) {
            const int i = (tt & 3) + 8 * (tt >> 2) + 4 * h;
            L.t1[wv][c5][i]      = t1_0[tt];
            L.t1[wv][c5][32 + i] = t1_1[tt];
        }
        __syncthreads();

        s8v bfh[4], bfl[4];
        #pragma unroll
        for (int n = 0; n < 4; ++n) {
            const float* p = &L.t1[wv][c5][n * 16 + 8 * h];
            float4 xa = *(const float4*)p, xb = *(const float4*)(p + 4);
            uint32 h0, l0, h1, l1, h2, l2, h3, l3;
            hl_pair(xa.x, xa.y, h0, l0);
            hl_pair(xa.z, xa.w, h1, l1);
            hl_pair(xb.x, xb.y, h2, l2);
            hl_pair(xb.z, xb.w, h3, l3);
            U4 uh = {h0, h1, h2, h3}, ul = {l0, l1, l2, l3};
            bfh[n] = __builtin_bit_cast(s8v, uh);
            bfl[n] = __builtin_bit_cast(s8v, ul);
        }

        #pragma unroll
        for (int At = 0; At < 2; ++At) {
            f16v y = fz;
            #pragma unroll
            for (int n = 0; n < 4; ++n) {
                s8v awh = *(const s8v*)(wort_h + (size_t)(32 * At + c5) * 64 + n * 16 + 8 * h);
                s8v awl = *(const s8v*)(wort_l + (size_t)(32 * At + c5) * 64 + n * 16 + 8 * h);
                y = __builtin_amdgcn_mfma_f32_32x32x16_bf16(awh, bfh[n], y, 0, 0, 0);
                y = __builtin_amdgcn_mfma_f32_32x32x16_bf16(awh, bfl[n], y, 0, 0, 0);
                y = __builtin_amdgcn_mfma_f32_32x32x16_bf16(awl, bfh[n], y, 0, 0, 0);
            }
            #pragma unroll
            for (int rg = 0; rg < 4; ++rg) {
                float4 bv = *(const float4*)(boT + c * 64 + 32 * At + 8 * rg + 4 * h);
                float be[4] = {bv.x, bv.y, bv.z, bv.w};
                #pragma unroll
                for (int e = 0; e < 4; ++e) {
                    const int a = 32 * At + 8 * rg + 4 * h + e;
                    out[(size_t)token * 4096 + a * 64 + c] = (y[rg * 4 + e] + be[e]) * INV_H;
                }
            }
        }
        __syncthreads();
    }
}

// ---------------------------------------------------------------------------
extern "C" void kernel_launch(void* const* d_in, const int* in_sizes, int n_in,
                              void* d_out, int out_size, void* d_ws, size_t ws_size,
                              hipStream_t stream) {
    const float* queries = (const float*)d_in[0];
    const float* keys    = (const float*)d_in[1];
    const float* values  = (const float*)d_in[2];
    const float* Wq_row  = (const float*)d_in[3];
    const float* Wq_col  = (const float*)d_in[4];
    const float* bq      = (const float*)d_in[5];
    const float* Wk_row  = (const float*)d_in[6];
    const float* Wk_col  = (const float*)d_in[7];
    const float* bk      = (const float*)d_in[8];
    const float* Wv_row  = (const float*)d_in[9];
    const float* Wv_col  = (const float*)d_in[10];
    const float* bv      = (const float*)d_in[11];
    const float* Wo_row  = (const float*)d_in[12];
    const float* Wo_col  = (const float*)d_in[13];
    const float* bo      = (const float*)d_in[14];
    float* out = (float*)d_out;

    const size_t SEP = (size_t)BB * HEADS * TT * 256;   // 786432 elements
    ushort_t* q_bf  = (ushort_t*)d_ws;
    ushort_t* k_bf  = q_bf + SEP;
    ushort_t* vt_bf = k_bf + SEP;
    float*    att   = (float*)(vt_bf + SEP);
    ushort_t* wct    = (ushort_t*)(att + SEP);
    ushort_t* wrt    = wct + 3 * 4096;
    float*    bT     = (float*)(wrt + 3 * 4096);
    ushort_t* woct_h = (ushort_t*)(bT + 3 * 4096);
    ushort_t* woct_l = woct_h + 4096;
    ushort_t* wort_h = woct_l + 4096;
    ushort_t* wort_l = wort_h + 4096;
    float*    boT    = (float*)(wort_l + 4096);

    // grid = co-resident capacity (cooperative requirement), capped at task max
    int maxb = 0;
    if (hipOccupancyMaxActiveBlocksPerMultiprocessor(
            &maxb, (const void*)fused_all, 256, 0) != hipSuccess || maxb < 1)
        maxb = 1;
    int grid = maxb * 256;
    if (grid > ATT_TASKS) grid = ATT_TASKS;

    void* args[] = {
        (void*)&queries, (void*)&keys, (void*)&values,
        (void*)&Wq_row, (void*)&Wq_col, (void*)&bq,
        (void*)&Wk_row, (void*)&Wk_col, (void*)&bk,
        (void*)&Wv_row, (void*)&Wv_col, (void*)&bv,
        (void*)&Wo_row, (void*)&Wo_col, (void*)&bo,
        (void*)&q_bf, (void*)&k_bf, (void*)&vt_bf, (void*)&att,
        (void*)&wct, (void*)&wrt, (void*)&bT,
        (void*)&woct_h, (void*)&woct_l, (void*)&wort_h, (void*)&wort_l, (void*)&boT,
        (void*)&out
    };

    hipLaunchCooperativeKernel((const void*)fused_all, dim3(grid), dim3(256),
                               args, 0, stream);
}

// Round 16
// 63.450 us; speedup vs baseline: 3.0908x; 3.0908x over previous
//
#include <hip/hip_runtime.h>
#include <hip/hip_bf16.h>
#include <math.h>

typedef unsigned int uint32;
typedef unsigned short ushort_t;
typedef __attribute__((ext_vector_type(8))) short s8v;
typedef __attribute__((ext_vector_type(16))) float f16v;
typedef __attribute__((ext_vector_type(2))) unsigned int u2v;

// Problem constants
#define LH 4
#define RH 4
#define DD 64
#define BB 2
#define TT 96
#define NTOK (BB*TT)           // 192
#define HEADS 16
#define VHEADS 10              // heads with r <= l
#define INV_H 0.0625f
#define LOG2E 1.4426950408889634f
#define QKV_BLOCKS 288         // 1152 waves / 4
#define ZF_BLOCKS 48           // att zerofill tail blocks

struct U4 { uint32 x, y, z, w; };

__device__ __forceinline__ uint32 f2bf(float f) {
    return (uint32)__builtin_bit_cast(ushort_t, __float2bfloat16(f));
}
__device__ __forceinline__ uint32 pkbf(float lo, float hi) {
    return f2bf(lo) | (f2bf(hi) << 16);
}
__device__ __forceinline__ float bf2f(uint32 u) {
    return __uint_as_float(u << 16);
}
// hi/lo split of a pair into packed bf16 words (3-product split-GEMM)
__device__ __forceinline__ void hl_pair(float v0, float v1, uint32 &hw, uint32 &lw) {
    uint32 h0 = f2bf(v0), h1 = f2bf(v1);
    hw = h0 | (h1 << 16);
    lw = pkbf(v0 - bf2f(h0), v1 - bf2f(h1));
}
// exchange lanes[0:31] of a with lanes[32:63] of b — verified for A-frags (R10)
__device__ __forceinline__ void hswap(uint32 &a, uint32 &b, int h) {
#if __has_builtin(__builtin_amdgcn_permlane32_swap)
    u2v rr = __builtin_amdgcn_permlane32_swap(a, b, false, false);
    a = rr.x; b = rr.y;
#else
    uint32 xa = (uint32)__shfl_xor((int)a, 32, 64);
    uint32 xb = (uint32)__shfl_xor((int)b, 32, 64);
    uint32 na = (h == 0) ? xb : a;
    uint32 nb = (h == 0) ? b  : xa;
    a = na; b = nb;
#endif
}

// ---------------------------------------------------------------------------
// MFMA q/k/v projections (R13-proven structure) with INLINE weight conversion:
// B/A fragments built directly from fp32 Wc/Wr via coalesced scalar loads
// (identical values to the old wprep tables — same f2bf, same order).
// Tail blocks zero the att buffer (r>l masked head blocks).
// ---------------------------------------------------------------------------
__global__ __launch_bounds__(256) void pdense_qkv_mfma(
    const float* __restrict__ Xq, const float* __restrict__ Xk, const float* __restrict__ Xv,
    const float* __restrict__ Wq_row, const float* __restrict__ Wq_col, const float* __restrict__ bq,
    const float* __restrict__ Wk_row, const float* __restrict__ Wk_col, const float* __restrict__ bk,
    const float* __restrict__ Wv_row, const float* __restrict__ Wv_col, const float* __restrict__ bv,
    ushort_t* __restrict__ q_bf, ushort_t* __restrict__ k_bf,
    ushort_t* __restrict__ vt_bf, float* __restrict__ att)
{
    __shared__ float lds_t1[4][32][68];   // per-wave slab: [c5][i], pad 68

    const int bid = blockIdx.x;
    if (bid >= QKV_BLOCKS) {
        const int zb = bid - QKV_BLOCKS;
        float4* a4 = (float4*)att;
        #pragma unroll
        for (int it = 0; it < 16; ++it)
            a4[(size_t)zb * 4096 + it * 256 + threadIdx.x] = float4{0.f, 0.f, 0.f, 0.f};
        return;
    }
    const int wv = threadIdx.x >> 6;
    const int task = bid * 4 + wv;                   // 0..1151
    const int proj = task / (NTOK * 2);
    const int rem  = task % (NTOK * 2);
    const int token = rem >> 1;
    const int ch = rem & 1;
    const int lane = threadIdx.x & 63;
    const int c5 = lane & 31, h = lane >> 5;
    const int c = ch * 32 + c5;
    const int bI = token / TT, t = token % TT;

    const float* X  = (proj == 0) ? Xq : (proj == 1) ? Xk : Xv;
    const float* Wc = (proj == 0) ? Wq_col : (proj == 1) ? Wk_col : Wv_col;
    const float* Wr = (proj == 0) ? Wq_row : (proj == 1) ? Wk_row : Wv_row;
    const float* bs = (proj == 0) ? bq : (proj == 1) ? bk : bv;
    const float* Xp = X + (size_t)token * 4096;
    const float scale = (proj == 0) ? (INV_H * INV_H * LOG2E) : INV_H;

    const f16v fz = {0,0,0,0,0,0,0,0,0,0,0,0,0,0,0,0};

    // GEMM1: T1 = X @ Wc ; lane (c5,h) reg t -> T1[i=(t&3)+8*(t>>2)+4h (+32)][c]
    f16v t1_0 = fz, t1_1 = fz;
    #pragma unroll
    for (int n = 0; n < 4; ++n) {
        const int k0 = n * 16 + 8 * h;
        // B-frag col c, rows k0..k0+7: Wc[j][c] (coalesced across lanes in c)
        U4 ub = { pkbf(Wc[(k0 + 0) * 64 + c], Wc[(k0 + 1) * 64 + c]),
                  pkbf(Wc[(k0 + 2) * 64 + c], Wc[(k0 + 3) * 64 + c]),
                  pkbf(Wc[(k0 + 4) * 64 + c], Wc[(k0 + 5) * 64 + c]),
                  pkbf(Wc[(k0 + 6) * 64 + c], Wc[(k0 + 7) * 64 + c]) };
        s8v bf = __builtin_bit_cast(s8v, ub);
        {
            const float* xr = Xp + (size_t)c5 * 64 + k0;
            float4 xa = *(const float4*)xr, xb = *(const float4*)(xr + 4);
            U4 u = { pkbf(xa.x, xa.y), pkbf(xa.z, xa.w), pkbf(xb.x, xb.y), pkbf(xb.z, xb.w) };
            t1_0 = __builtin_amdgcn_mfma_f32_32x32x16_bf16(__builtin_bit_cast(s8v, u), bf, t1_0, 0, 0, 0);
        }
        {
            const float* xr = Xp + (size_t)(32 + c5) * 64 + k0;
            float4 xa = *(const float4*)xr, xb = *(const float4*)(xr + 4);
            U4 u = { pkbf(xa.x, xa.y), pkbf(xa.z, xa.w), pkbf(xb.x, xb.y), pkbf(xb.z, xb.w) };
            t1_1 = __builtin_amdgcn_mfma_f32_32x32x16_bf16(__builtin_bit_cast(s8v, u), bf, t1_1, 0, 0, 0);
        }
    }

    // LDS transpose roundtrip (PROVEN B-frag rebuild)
    #pragma unroll
    for (int tt = 0; tt < 16; ++tt) {
        const int i = (tt & 3) + 8 * (tt >> 2) + 4 * h;
        lds_t1[wv][c5][i]      = t1_0[tt];
        lds_t1[wv][c5][32 + i] = t1_1[tt];
    }
    __syncthreads();

    s8v bfr[4];
    #pragma unroll
    for (int n = 0; n < 4; ++n) {
        const float* p = &lds_t1[wv][c5][n * 16 + 8 * h];
        float4 xa = *(const float4*)p, xb = *(const float4*)(p + 4);
        U4 u = { pkbf(xa.x, xa.y), pkbf(xa.z, xa.w), pkbf(xb.x, xb.y), pkbf(xb.z, xb.w) };
        bfr[n] = __builtin_bit_cast(s8v, u);
    }

    // GEMM2 + epilogue
    #pragma unroll
    for (int At = 0; At < 2; ++At) {
        const int a0 = 32 * At + c5;
        f16v y = fz;
        #pragma unroll
        for (int n = 0; n < 4; ++n) {
            const int k0 = n * 16 + 8 * h;
            // A-frag row a0, k = i = k0..k0+7: Wr[i][a0] (coalesced in a0)
            U4 ua = { pkbf(Wr[(k0 + 0) * 64 + a0], Wr[(k0 + 1) * 64 + a0]),
                      pkbf(Wr[(k0 + 2) * 64 + a0], Wr[(k0 + 3) * 64 + a0]),
                      pkbf(Wr[(k0 + 4) * 64 + a0], Wr[(k0 + 5) * 64 + a0]),
                      pkbf(Wr[(k0 + 6) * 64 + a0], Wr[(k0 + 7) * 64 + a0]) };
            y = __builtin_amdgcn_mfma_f32_32x32x16_bf16(
                    __builtin_bit_cast(s8v, ua), bfr[n], y, 0, 0, 0);
        }
        #pragma unroll
        for (int rg = 0; rg < 4; ++rg) {
            #pragma unroll
            for (int e = 0; e < 4; ++e) {
                const int a = 32 * At + 8 * rg + 4 * h + e;
                const float val = (y[rg * 4 + e] + bs[a * 64 + c]) * scale;
                const ushort_t ov = (ushort_t)f2bf(val);
                const size_t base =
                    ((size_t)((bI * HEADS + (a >> 4) * RH + (c >> 4)) * TT + t)) * 256;
                if (proj == 0)      q_bf[base + (a & 15) * 16 + (c & 15)] = ov;
                else if (proj == 1) k_bf[base + (a & 15) * 16 + (c & 15)] = ov;
                else                vt_bf[base + (c & 15) * 16 + (a & 15)] = ov;
            }
        }
    }
}

// ---------------------------------------------------------------------------
// MFMA out-projection (R14-proven hi/lo 3-product) with INLINE hi/lo weight
// conversion from fp32 Wo_col/Wo_row. 1 wave per (token, col-half).
// ---------------------------------------------------------------------------
__global__ __launch_bounds__(256) void pdense_out_mfma2(
    const float* __restrict__ att,
    const float* __restrict__ Wo_row, const float* __restrict__ Wo_col,
    const float* __restrict__ bo, float* __restrict__ out)
{
    __shared__ float lds_t1[4][32][68];

    const int wv = threadIdx.x >> 6;
    const int task = blockIdx.x * 4 + wv;            // 0..383
    const int token = task >> 1, ch = task & 1;
    const int lane = threadIdx.x & 63;
    const int c5 = lane & 31, h = lane >> 5;
    const int c = ch * 32 + c5;

    const float* Xp = att + (size_t)token * 4096;
    const f16v fz = {0,0,0,0,0,0,0,0,0,0,0,0,0,0,0,0};

    // GEMM1: T1 = att @ Wo_col (A = att hi/lo, B = Wo_col hi/lo, 3 products)
    f16v t1_0 = fz, t1_1 = fz;
    #pragma unroll
    for (int n = 0; n < 4; ++n) {
        const int k0 = n * 16 + 8 * h;
        uint32 bh0, bl0, bh1, bl1, bh2, bl2, bh3, bl3;
        hl_pair(Wo_col[(k0 + 0) * 64 + c], Wo_col[(k0 + 1) * 64 + c], bh0, bl0);
        hl_pair(Wo_col[(k0 + 2) * 64 + c], Wo_col[(k0 + 3) * 64 + c], bh1, bl1);
        hl_pair(Wo_col[(k0 + 4) * 64 + c], Wo_col[(k0 + 5) * 64 + c], bh2, bl2);
        hl_pair(Wo_col[(k0 + 6) * 64 + c], Wo_col[(k0 + 7) * 64 + c], bh3, bl3);
        U4 ubh = {bh0, bh1, bh2, bh3}, ubl = {bl0, bl1, bl2, bl3};
        s8v bh = __builtin_bit_cast(s8v, ubh), bl = __builtin_bit_cast(s8v, ubl);
        #pragma unroll
        for (int T = 0; T < 2; ++T) {
            const float* xr = Xp + (size_t)(32 * T + c5) * 64 + k0;
            float4 xa = *(const float4*)xr, xb = *(const float4*)(xr + 4);
            uint32 hw0, lw0, hw1, lw1, hw2, lw2, hw3, lw3;
            hl_pair(xa.x, xa.y, hw0, lw0);
            hl_pair(xa.z, xa.w, hw1, lw1);
            hl_pair(xb.x, xb.y, hw2, lw2);
            hl_pair(xb.z, xb.w, hw3, lw3);
            U4 uh = {hw0, hw1, hw2, hw3}, ul = {lw0, lw1, lw2, lw3};
            s8v ah = __builtin_bit_cast(s8v, uh), al = __builtin_bit_cast(s8v, ul);
            f16v acc = (T == 0) ? t1_0 : t1_1;
            acc = __builtin_amdgcn_mfma_f32_32x32x16_bf16(ah, bh, acc, 0, 0, 0);
            acc = __builtin_amdgcn_mfma_f32_32x32x16_bf16(al, bh, acc, 0, 0, 0);
            acc = __builtin_amdgcn_mfma_f32_32x32x16_bf16(ah, bl, acc, 0, 0, 0);
            if (T == 0) t1_0 = acc; else t1_1 = acc;
        }
    }

    // LDS roundtrip: [c5][i] then read back contiguous, hi/lo split
    #pragma unroll
    for (int tt = 0; tt < 16; ++tt) {
        const int i = (tt & 3) + 8 * (tt >> 2) + 4 * h;
        lds_t1[wv][c5][i]      = t1_0[tt];
        lds_t1[wv][c5][32 + i] = t1_1[tt];
    }
    __syncthreads();

    s8v bfh[4], bfl[4];
    #pragma unroll
    for (int n = 0; n < 4; ++n) {
        const float* p = &lds_t1[wv][c5][n * 16 + 8 * h];
        float4 xa = *(const float4*)p, xb = *(const float4*)(p + 4);
        uint32 h0, l0, h1, l1, h2, l2, h3, l3;
        hl_pair(xa.x, xa.y, h0, l0);
        hl_pair(xa.z, xa.w, h1, l1);
        hl_pair(xb.x, xb.y, h2, l2);
        hl_pair(xb.z, xb.w, h3, l3);
        U4 uh = {h0, h1, h2, h3}, ul = {l0, l1, l2, l3};
        bfh[n] = __builtin_bit_cast(s8v, uh);
        bfl[n] = __builtin_bit_cast(s8v, ul);
    }

    // GEMM2: Y = Wo_row^T @ T1 (A = Wo_row hi/lo inline) + bias, /h
    #pragma unroll
    for (int At = 0; At < 2; ++At) {
        const int a0 = 32 * At + c5;
        f16v y = fz;
        #pragma unroll
        for (int n = 0; n < 4; ++n) {
            const int k0 = n * 16 + 8 * h;
            uint32 ah0, al0, ah1, al1, ah2, al2, ah3, al3;
            hl_pair(Wo_row[(k0 + 0) * 64 + a0], Wo_row[(k0 + 1) * 64 + a0], ah0, al0);
            hl_pair(Wo_row[(k0 + 2) * 64 + a0], Wo_row[(k0 + 3) * 64 + a0], ah1, al1);
            hl_pair(Wo_row[(k0 + 4) * 64 + a0], Wo_row[(k0 + 5) * 64 + a0], ah2, al2);
            hl_pair(Wo_row[(k0 + 6) * 64 + a0], Wo_row[(k0 + 7) * 64 + a0], ah3, al3);
            U4 uah = {ah0, ah1, ah2, ah3}, ual = {al0, al1, al2, al3};
            s8v awh = __builtin_bit_cast(s8v, uah), awl = __builtin_bit_cast(s8v, ual);
            y = __builtin_amdgcn_mfma_f32_32x32x16_bf16(awh, bfh[n], y, 0, 0, 0);
            y = __builtin_amdgcn_mfma_f32_32x32x16_bf16(awh, bfl[n], y, 0, 0, 0);
            y = __builtin_amdgcn_mfma_f32_32x32x16_bf16(awl, bfh[n], y, 0, 0, 0);
        }
        #pragma unroll
        for (int rg = 0; rg < 4; ++rg) {
            #pragma unroll
            for (int e = 0; e < 4; ++e) {
                const int a = 32 * At + 8 * rg + 4 * h + e;
                out[(size_t)token * 4096 + a * 64 + c] =
                    (y[rg * 4 + e] + bo[a * 64 + c]) * INV_H;
            }
        }
    }
}

// ---------------------------------------------------------------------------
// MFMA attention v2 (verbatim R10/R13/R14, verified).
// ---------------------------------------------------------------------------
__global__ __launch_bounds__(256, 4) void attn_kernel(
    const ushort_t* __restrict__ q_bf,
    const ushort_t* __restrict__ k_bf,
    const ushort_t* __restrict__ vt_bf,
    float* __restrict__ att)
{
    __shared__ float lds_z[4][64][9];
    __shared__ float lds_pv[4][64][17];

    const int ip = blockIdx.x % (TT / 2);
    const int vh = (blockIdx.x / (TT / 2)) % VHEADS;
    const int bI = blockIdx.x / ((TT / 2) * VHEADS);
    const int l = (vh >= 1) + (vh >= 3) + (vh >= 6);
    const int r = vh - (l * (l + 1)) / 2;
    const int head = l * RH + r;
    const int i0 = ip * 2;
    const int lane = threadIdx.x & 63;
    const int wv = threadIdx.x >> 6;
    const int c5 = lane & 31;
    const int h  = lane >> 5;

    const size_t hb = (size_t)(bI * HEADS + head) * TT * 256;
    const int frow = (c5 & 15) * 16 + 8 * h;

    s8v qf = *(const s8v*)(q_bf + hb + (size_t)(i0 + (c5 >> 4)) * 256 + frow);
    const ushort_t* kb = k_bf + hb + frow;
    const ushort_t* vb = vt_bf + hb + frow;

    const int jb = wv * (TT / 4);
    const f16v fz16 = {0,0,0,0,0,0,0,0,0,0,0,0,0,0,0,0};

    float ls[8] = {0,0,0,0,0,0,0,0};
    #pragma unroll 3
    for (int jp = 0; jp < 12; ++jp) {
        const int j0g = jb + jp * 2;
        s8v kf = *(const s8v*)(kb + (size_t)(j0g + (c5 >> 4)) * 256);
        f16v d = __builtin_amdgcn_mfma_f32_32x32x16_bf16(kf, qf, fz16, 0, 0, 0);
        #pragma unroll
        for (int t = 0; t < 8; ++t)
            ls[t] += exp2f(d[t]) + exp2f(d[t + 8]);
    }
    #pragma unroll
    for (int t = 0; t < 8; ++t) lds_z[wv][lane][t] = ls[t];
    __syncthreads();
    float inv[8];
    #pragma unroll
    for (int t = 0; t < 8; ++t) {
        float s = lds_z[0][lane][t] + lds_z[1][lane][t]
                + lds_z[2][lane][t] + lds_z[3][lane][t];
        inv[t] = 1.f / s;
    }

    f16v pv = fz16;
    #pragma unroll 2
    for (int jp = 0; jp < 12; ++jp) {
        const int j0g = jb + jp * 2;
        s8v kf = *(const s8v*)(kb + (size_t)(j0g + (c5 >> 4)) * 256);
        f16v d = __builtin_amdgcn_mfma_f32_32x32x16_bf16(kf, qf, fz16, 0, 0, 0);
        float w[16];
        #pragma unroll
        for (int t = 0; t < 8; ++t) {
            w[t]     = exp2f(d[t])     * inv[t];
            w[t + 8] = exp2f(d[t + 8]) * inv[t];
        }
        uint32 A0 = pkbf(w[0],  w[1]),  A1 = pkbf(w[2],  w[3]);
        uint32 A2 = pkbf(w[4],  w[5]),  A3 = pkbf(w[6],  w[7]);
        uint32 B0 = pkbf(w[8],  w[9]),  B1 = pkbf(w[10], w[11]);
        uint32 B2 = pkbf(w[12], w[13]), B3 = pkbf(w[14], w[15]);
        hswap(A2, A0, h); hswap(A3, A1, h);
        hswap(B2, B0, h); hswap(B3, B1, h);
        U4 fa = {A0, A1, A2, A3};
        U4 fb = {B0, B1, B2, B3};
        s8v vf0 = *(const s8v*)(vb + (size_t)(j0g + 0) * 256);
        s8v vf1 = *(const s8v*)(vb + (size_t)(j0g + 1) * 256);
        pv = __builtin_amdgcn_mfma_f32_32x32x16_bf16(__builtin_bit_cast(s8v, fa), vf0, pv, 0, 0, 0);
        pv = __builtin_amdgcn_mfma_f32_32x32x16_bf16(__builtin_bit_cast(s8v, fb), vf1, pv, 0, 0, 0);
    }

    #pragma unroll
    for (int t = 0; t < 16; ++t) lds_pv[wv][lane][t] = pv[t];
    __syncthreads();

    if (c5 < 16) {
        #pragma unroll
        for (int rr = 0; rr < 4; ++rr) {
            const int reg = wv * 4 + rr;
            float v = lds_pv[0][lane][reg] + lds_pv[1][lane][reg]
                    + lds_pv[2][lane][reg] + lds_pv[3][lane][reg];
            const int row = rr + 8 * wv + 4 * h;
            const int i = row >> 4, p = row & 15;
            att[((size_t)(bI * TT + i0 + i) * DD + l * 16 + p) * DD + r * 16 + c5] = v;
        }
    }
}

// ---------------------------------------------------------------------------
extern "C" void kernel_launch(void* const* d_in, const int* in_sizes, int n_in,
                              void* d_out, int out_size, void* d_ws, size_t ws_size,
                              hipStream_t stream) {
    const float* queries = (const float*)d_in[0];
    const float* keys    = (const float*)d_in[1];
    const float* values  = (const float*)d_in[2];
    const float* Wq_row  = (const float*)d_in[3];
    const float* Wq_col  = (const float*)d_in[4];
    const float* bq      = (const float*)d_in[5];
    const float* Wk_row  = (const float*)d_in[6];
    const float* Wk_col  = (const float*)d_in[7];
    const float* bk      = (const float*)d_in[8];
    const float* Wv_row  = (const float*)d_in[9];
    const float* Wv_col  = (const float*)d_in[10];
    const float* bv      = (const float*)d_in[11];
    const float* Wo_row  = (const float*)d_in[12];
    const float* Wo_col  = (const float*)d_in[13];
    const float* bo      = (const float*)d_in[14];
    float* out = (float*)d_out;

    const size_t SEP = (size_t)BB * HEADS * TT * 256;   // 786432 elements
    ushort_t* q_bf  = (ushort_t*)d_ws;
    ushort_t* k_bf  = q_bf + SEP;
    ushort_t* vt_bf = k_bf + SEP;
    float*    att   = (float*)(vt_bf + SEP);

    pdense_qkv_mfma<<<QKV_BLOCKS + ZF_BLOCKS, 256, 0, stream>>>(
        queries, keys, values,
        Wq_row, Wq_col, bq, Wk_row, Wk_col, bk, Wv_row, Wv_col, bv,
        q_bf, k_bf, vt_bf, att);

    attn_kernel<<<BB * VHEADS * (TT / 2), 256, 0, stream>>>(q_bf, k_bf, vt_bf, att);

    pdense_out_mfma2<<<NTOK * 2 / 4, 256, 0, stream>>>(
        att, Wo_row, Wo_col, bo, out);
}